// Round 10
// baseline (268.911 us; speedup 1.0000x reference)
//
#include <hip/hip_runtime.h>
#include <math.h>

#define BB 8
#define LL 2048
#define DD 512
#define HH 8
#define DHH 64
#define KD 8
#define MM (BB*LL)   // 16384

typedef _Float16 f16x2 __attribute__((ext_vector_type(2)));
typedef _Float16 f16x4 __attribute__((ext_vector_type(4)));
typedef _Float16 f16x8 __attribute__((ext_vector_type(8)));
typedef float    f32x4 __attribute__((ext_vector_type(4)));

// ---------------- prep: weights only, fp32 -> fp16 hi/lo ----------------
__device__ inline void cvt8(const float* __restrict__ s, _Float16* hp, _Float16* lp) {
    const float4 a = *(const float4*)s;
    const float4 b = *(const float4*)(s + 4);
    const float v[8] = {a.x, a.y, a.z, a.w, b.x, b.y, b.z, b.w};
    f16x8 hi, lo;
#pragma unroll
    for (int j = 0; j < 8; j++) {
        const _Float16 h = (_Float16)v[j];
        hi[j] = h;
        lo[j] = (_Float16)((v[j] - (float)h) * 512.0f);
    }
    *(f16x8*)hp = hi;
    if (lp) *(f16x8*)lp = lo;
}

__global__ __launch_bounds__(256) void prep_w(const float* __restrict__ Wq, const float* __restrict__ Wk,
                                              const float* __restrict__ Wv, const float* __restrict__ Wo,
                                              _Float16* __restrict__ Wq_h, _Float16* __restrict__ Wq_l,
                                              _Float16* __restrict__ Wk_h, _Float16* __restrict__ Wk_l,
                                              _Float16* __restrict__ Wv_h, _Float16* __restrict__ Wo_h) {
    const int g = blockIdx.x * 256 + threadIdx.x;   // 131072 threads × 8 elems
    const int which = g >> 15;
    const size_t idx = (size_t)(g & 32767) * 8;
    if (which == 0)      cvt8(Wq + idx, Wq_h + idx, Wq_l + idx);
    else if (which == 1) cvt8(Wk + idx, Wk_h + idx, Wk_l + idx);
    else if (which == 2) cvt8(Wv + idx, Wv_h + idx, nullptr);
    else                 cvt8(Wo + idx, Wo_h + idx, nullptr);
}

// ---------------- async global->LDS staging (DMA, no VGPR round-trip) ----------------
__device__ __forceinline__ void stage16(const _Float16* g, const _Float16* l) {
    __builtin_amdgcn_global_load_lds(
        (const __attribute__((address_space(1))) void*)g,
        (__attribute__((address_space(3))) void*)l,
        16, 0, 0);
}

// ---------------- MFMA GEMM body (device fn): C = A @ B^T + bias ----------------
// Templated K-step BK (32 or 64). BK=64 halves barrier count; LDS 64KB keeps
// 2 blocks/CU. Chunk-XOR swizzle; 2-way bank alias = free.
// B staged via global_load_lds width=16; A (AF32=1) software-pipelined from fp32.
template<int NPROD, int MODE, int AF32, int BK>
__device__ __forceinline__ void gemm_body(const float* __restrict__ A32,
                                          const _Float16* __restrict__ Ag,
                                          const _Float16* __restrict__ Al_g,
                                          const _Float16* __restrict__ Bg,
                                          const _Float16* __restrict__ Bl_g,
                                          const float* __restrict__ bias,
                                          void* __restrict__ Cv,
                                          _Float16* lds, int l0) {
    constexpr int CPR  = BK / 8;        // chunks (16B) per row
    constexpr int NST  = BK / 16;       // staging iterations per plane
    constexpr int SH   = (BK == 32) ? 2 : 3;
    constexpr int PLN  = 128 * BK;      // plane size in halves

#define SWZR(R) ((BK == 32) ? (((R) >> 1) & 3) : ((R) & 7))
#define ASWZ(R, g) ((size_t)(R) * BK + (size_t)((((g) ^ SWZR(R))) * 8))

    _Float16* Ah = lds;
    _Float16* Bh = lds + PLN;
    _Float16* Al = (NPROD == 3) ? lds + 2 * PLN : lds;
    _Float16* Bl = (NPROD == 3) ? lds + 3 * PLN : lds;

    const int t  = threadIdx.x;
    const int m0 = (((l0 >> 5) << 3) | (l0 & 7)) * 128;   // XCD-aware swizzle
    const int n0 = ((l0 >> 3) & 3) * 128;

    const int wv   = t >> 6;
    const int lane = t & 63;
    const int wm   = (wv >> 1) * 64;
    const int wn   = (wv & 1) * 64;
    const int lm   = lane & 15;
    const int quad = lane >> 4;

    // staging geometry: wave wv, iter i covers LDS slots s = (i*4+wv)*64 + lane
    int srow[NST], schk[NST], sgrp[NST];
#pragma unroll
    for (int i = 0; i < NST; i++) {
        const int s = (i * 4 + wv) * 64 + lane;
        srow[i] = s >> SH;
        schk[i] = (s & (CPR - 1)) ^ SWZR(srow[i]);
        sgrp[i] = (i * 4 + wv) * 512;    // wave-uniform LDS base (halves)
    }

    f32x4 acc0[4][4] = {};
    f32x4 acc1[4][4] = {};

    // A fp32 pipeline registers (loaded one K-step ahead)
    float4 vaA[NST], vaB[NST];
    if (AF32) {
#pragma unroll
        for (int i = 0; i < NST; i++) {
            const float* src = A32 + (size_t)(m0 + srow[i]) * 512 + schk[i] * 8;
            vaA[i] = *(const float4*)src;
            vaB[i] = *(const float4*)(src + 4);
        }
    }

    for (int k0 = 0; k0 < 512; k0 += BK) {
        __syncthreads();   // previous iteration's fragment reads complete
#pragma unroll
        for (int i = 0; i < NST; i++) {
            const size_t offB = (size_t)(n0 + srow[i]) * 512 + k0 + schk[i] * 8;
            stage16(Bg + offB, Bh + sgrp[i]);
            if (NPROD == 3) stage16(Bl_g + offB, Bl + sgrp[i]);
            if (AF32) {
                const float va[8] = {vaA[i].x, vaA[i].y, vaA[i].z, vaA[i].w,
                                     vaB[i].x, vaB[i].y, vaB[i].z, vaB[i].w};
                f16x8 hi, lo;
#pragma unroll
                for (int j = 0; j < 8; j++) {
                    const _Float16 h = (_Float16)va[j];
                    hi[j] = h;
                    if (NPROD == 3) lo[j] = (_Float16)((va[j] - (float)h) * 512.0f);
                }
                *(f16x8*)&Ah[sgrp[i] + lane * 8] = hi;
                if (NPROD == 3) *(f16x8*)&Al[sgrp[i] + lane * 8] = lo;
            } else {
                const size_t offA = (size_t)(m0 + srow[i]) * 512 + k0 + schk[i] * 8;
                stage16(Ag + offA, Ah + sgrp[i]);
                if (NPROD == 3) stage16(Al_g + offA, Al + sgrp[i]);
            }
        }
        __syncthreads();   // vmcnt+lgkmcnt drain before barrier (compiler)

        if (AF32 && k0 + BK < 512) {   // issue next-step A loads; hide under MFMA phase
#pragma unroll
            for (int i = 0; i < NST; i++) {
                const float* src = A32 + (size_t)(m0 + srow[i]) * 512 + (k0 + BK) + schk[i] * 8;
                vaA[i] = *(const float4*)src;
                vaB[i] = *(const float4*)(src + 4);
            }
        }

#pragma unroll
        for (int ks = 0; ks < BK / 32; ks++) {
            const int gq = ks * 4 + quad;     // k-chunk for this 32-k slice
            f16x8 afh[4], bf[4];
#pragma unroll
            for (int mt = 0; mt < 4; mt++)
                afh[mt] = *(f16x8*)&Ah[ASWZ(wm + mt * 16 + lm, gq)];
#pragma unroll
            for (int nt = 0; nt < 4; nt++)
                bf[nt] = *(f16x8*)&Bh[ASWZ(wn + nt * 16 + lm, gq)];

#pragma unroll
            for (int mt = 0; mt < 4; mt++)
#pragma unroll
                for (int nt = 0; nt < 4; nt++)
                    acc0[mt][nt] = __builtin_amdgcn_mfma_f32_16x16x32_f16(afh[mt], bf[nt], acc0[mt][nt], 0, 0, 0);

            if (NPROD == 3) {
                f16x8 afl[4];
#pragma unroll
                for (int mt = 0; mt < 4; mt++)
                    afl[mt] = *(f16x8*)&Al[ASWZ(wm + mt * 16 + lm, gq)];
#pragma unroll
                for (int mt = 0; mt < 4; mt++)
#pragma unroll
                    for (int nt = 0; nt < 4; nt++)
                        acc1[mt][nt] = __builtin_amdgcn_mfma_f32_16x16x32_f16(afl[mt], bf[nt], acc1[mt][nt], 0, 0, 0);
#pragma unroll
                for (int nt = 0; nt < 4; nt++)
                    bf[nt] = *(f16x8*)&Bl[ASWZ(wn + nt * 16 + lm, gq)];
#pragma unroll
                for (int mt = 0; mt < 4; mt++)
#pragma unroll
                    for (int nt = 0; nt < 4; nt++)
                        acc1[mt][nt] = __builtin_amdgcn_mfma_f32_16x16x32_f16(afh[mt], bf[nt], acc1[mt][nt], 0, 0, 0);
            }
        }
    }
#undef ASWZ
#undef SWZR

    // epilogue: C/D layout col=lane&15, row=quad*4+reg
#pragma unroll
    for (int mt = 0; mt < 4; mt++) {
#pragma unroll
        for (int nt = 0; nt < 4; nt++) {
            const int n = n0 + wn + nt * 16 + lm;
            const float bv = bias[n];
            float val[4];
#pragma unroll
            for (int r = 0; r < 4; r++) {
                val[r] = acc0[mt][nt][r] + bv;
                if (NPROD == 3) val[r] += acc1[mt][nt][r] * (1.0f / 512.0f);
            }
            const int mbase = m0 + wm + mt * 16 + quad * 4;   // multiple of 4
            const int b_idx = mbase >> 11;
            const int lbase = mbase & 2047;
            if (MODE == 0) {
                float* C = (float*)Cv;
#pragma unroll
                for (int r = 0; r < 4; r++) C[(size_t)(mbase + r) * 512 + n] = val[r];
            } else if (MODE == 1) {
                float* C = (float*)Cv;
                float4 pv = make_float4(val[0], val[1], val[2], val[3]);
                *(float4*)&C[((size_t)(b_idx * 512 + n)) * 2048 + lbase] = pv;
            } else {
                _Float16* C = (_Float16*)Cv;
#pragma unroll
                for (int r = 0; r < 4; r++)
                    C[(size_t)b_idx * 1048576 + (size_t)(n >> 6) * 131072
                      + (size_t)(lbase + r) * 64 + (n & 63)] = (_Float16)val[r];
            }
        }
    }
}

// merged q+k projection: 1024 blocks; 0-511 = q (A=x_q fp32), 512-1023 = k (A=x_kv fp32)
__global__ __launch_bounds__(256, 2) void gemm_qk(const float* __restrict__ A0f,
                                                  const _Float16* __restrict__ B0h, const _Float16* __restrict__ B0l,
                                                  const float* __restrict__ bias0, float* __restrict__ C0,
                                                  const float* __restrict__ A1f,
                                                  const _Float16* __restrict__ B1h, const _Float16* __restrict__ B1l,
                                                  const float* __restrict__ bias1, float* __restrict__ C1) {
    __shared__ __align__(16) _Float16 lds[32768];   // 4 planes x 16KB = 64KB
    const int prob = blockIdx.x >> 9;
    const int l0   = blockIdx.x & 511;
    if (prob == 0)
        gemm_body<3, 1, 1, 64>(A0f, nullptr, nullptr, B0h, B0l, bias0, C0, lds, l0);
    else
        gemm_body<3, 1, 1, 64>(A1f, nullptr, nullptr, B1h, B1l, bias1, C1, lds, l0);
}

// ======== fused gather + output projection: out = (Σ_k w·shift(V,d_k)) @ Wo^T + bo ========
// The A-tile IS the gather result. R2's version exposed the gather L2 latency serially
// (computed right before the barrier). Fixed with the R8-proven placement: V-loads for
// K-step k0+BK issued during k0's MFMA phase (>=400 cyc of hiding), fmaf+cvt+ds_write
// in the next staging phase. fmaf chain order == gather_ws -> bit-identical f16 A values.
__global__ __launch_bounds__(256, 2) void gemm_og(const _Float16* __restrict__ vh,
                                                  const int* __restrict__ delays,
                                                  const float* __restrict__ weights,
                                                  const _Float16* __restrict__ Bg,     // Wo_h
                                                  const float* __restrict__ bias,
                                                  float* __restrict__ C) {
    __shared__ __align__(16) _Float16 lds[8192];
    _Float16* Ah = lds;            // [128][32] chunk-swizzled
    _Float16* Bh = lds + 4096;

    const int t  = threadIdx.x;
    const int l0 = blockIdx.x;
    const int m0 = (((l0 >> 5) << 3) | (l0 & 7)) * 128;
    const int n0 = ((l0 >> 3) & 3) * 128;

    const int wv   = t >> 6;
    const int lane = t & 63;
    const int wm   = (wv >> 1) * 64;
    const int wn   = (wv & 1) * 64;
    const int lm   = lane & 15;
    const int quad = lane >> 4;

    int srow[2], schk[2], sgrp[2];
#pragma unroll
    for (int i = 0; i < 2; i++) {
        const int s = (i * 4 + wv) * 64 + lane;
        srow[i] = s >> 2;
        schk[i] = (s & 3) ^ ((srow[i] >> 1) & 3);
        sgrp[i] = (i * 4 + wv) * 512;
    }
#define OSWZ(R, g) ((size_t)(R) * 32 + (size_t)((((g) ^ (((R) >> 1) & 3))) * 8))

    const int bb  = m0 >> 11;       // batch (tile never crosses b: 2048 % 128 == 0)
    const int lml = m0 & 2047;      // l-base of tile

    f32x4 acc0[4][4] = {};

    // V-gather operand pipeline (one K-step ahead): 16 x f16x8 = 64 VGPRs
    f16x8 pv[2][KD];
#pragma unroll
    for (int i = 0; i < 2; i++) {   // prologue prefetch for k0 = 0 (head 0)
        const int bh = bb * 8;
        const int l  = lml + srow[i];
        const int dh = schk[i] * 8;
#pragma unroll
        for (int j = 0; j < KD; j++) {
            const int d = delays[bh * KD + j];
            const int pos = (l + d) & 2047;
            pv[i][j] = *(const f16x8*)&vh[(size_t)bh * 131072 + pos * 64 + dh];
        }
    }

    for (int k0 = 0; k0 < 512; k0 += 32) {
        const int bh = bb * 8 + (k0 >> 6);   // block-uniform -> scalar loads
        float wj[KD];
#pragma unroll
        for (int j = 0; j < KD; j++) wj[j] = weights[bh * KD + j];

        __syncthreads();   // previous iteration's fragment reads complete
#pragma unroll
        for (int i = 0; i < 2; i++) {
            float a[8] = {};
#pragma unroll
            for (int j = 0; j < KD; j++)
#pragma unroll
                for (int e = 0; e < 8; e++) a[e] = fmaf(wj[j], (float)pv[i][j][e], a[e]);
            f16x8 ov;
#pragma unroll
            for (int e = 0; e < 8; e++) ov[e] = (_Float16)a[e];
            *(f16x8*)&Ah[sgrp[i] + lane * 8] = ov;
            const size_t offB = (size_t)(n0 + srow[i]) * 512 + k0 + schk[i] * 8;
            stage16(Bg + offB, Bh + sgrp[i]);
        }
        __syncthreads();   // lgkmcnt+vmcnt drain (compiler)

        if (k0 + 32 < 512) {           // prefetch next K-step's V operands under MFMA
            const int kn  = k0 + 32;
            const int bhn = bb * 8 + (kn >> 6);
#pragma unroll
            for (int i = 0; i < 2; i++) {
                const int l  = lml + srow[i];
                const int dh = (kn & 63) + schk[i] * 8;
#pragma unroll
                for (int j = 0; j < KD; j++) {
                    const int d = delays[bhn * KD + j];
                    const int pos = (l + d) & 2047;
                    pv[i][j] = *(const f16x8*)&vh[(size_t)bhn * 131072 + pos * 64 + dh];
                }
            }
        }

        f16x8 afh[4], bf[4];
#pragma unroll
        for (int mt = 0; mt < 4; mt++)
            afh[mt] = *(f16x8*)&Ah[OSWZ(wm + mt * 16 + lm, quad)];
#pragma unroll
        for (int nt = 0; nt < 4; nt++)
            bf[nt] = *(f16x8*)&Bh[OSWZ(wn + nt * 16 + lm, quad)];

#pragma unroll
        for (int mt = 0; mt < 4; mt++)
#pragma unroll
            for (int nt = 0; nt < 4; nt++)
                acc0[mt][nt] = __builtin_amdgcn_mfma_f32_16x16x32_f16(afh[mt], bf[nt], acc0[mt][nt], 0, 0, 0);
    }
#undef OSWZ

    // epilogue: fp32 C[m*512+n]
#pragma unroll
    for (int mt = 0; mt < 4; mt++) {
#pragma unroll
        for (int nt = 0; nt < 4; nt++) {
            const int n  = n0 + wn + nt * 16 + lm;
            const float bv = bias[n];
            const int mbase = m0 + wm + mt * 16 + quad * 4;
#pragma unroll
            for (int r = 0; r < 4; r++)
                C[(size_t)(mbase + r) * 512 + n] = acc0[mt][nt][r] + bv;
        }
    }
}

// ============== register-resident radix-8 DIF forward FFT (N=2048), fp32 in ==============
// 1024 blocks × 4 sequences. Next-seq loads prefetched across the butterfly rounds.
#define PAD3(i) ((i) + ((i) >> 3))

__device__ inline float2 cmul2(float2 a, float2 w) {
    return make_float2(a.x * w.x - a.y * w.y, a.x * w.y + a.y * w.x);
}
__device__ inline float2 cadd2(float2 a, float2 b) { return make_float2(a.x + b.x, a.y + b.y); }
__device__ inline float2 csub2(float2 a, float2 b) { return make_float2(a.x - b.x, a.y - b.y); }

__global__ __launch_bounds__(256) void fft_fwd(const float* __restrict__ qT,
                                               const float* __restrict__ kT,
                                               float* __restrict__ specP) {
    const int blk  = blockIdx.x;     // bh*16 + part
    const int bh   = blk >> 4;
    const int part = blk & 15;
    const int t    = threadIdx.x;
    __shared__ float2 Zs[2304];      // PAD3(2047) = 2302
    __shared__ float2 Wt[1024];      // Wt[j] = exp(-2*pi*i*j/2048)

#pragma unroll
    for (int s = 0; s < 4; s++) {
        const int j = t + s * 256;
        float sv, cv;
        __sincosf(2.0f * (float)M_PI * (float)j / 2048.0f, &sv, &cv);
        Wt[j] = make_float2(cv, -sv);
    }

    float2 pacc[8];
#pragma unroll
    for (int s = 0; s < 8; s++) pacc[s] = make_float2(0.0f, 0.0f);

    const int low5 = t & 31, hi3 = t >> 5;
    const int low2 = t & 3,  hi6 = t >> 2;

    // prefetch first sequence
    float2 zn[8];
    {
        const int seq0 = bh * 64 + part * 4;
        const float* qp = qT + (size_t)seq0 * 2048;
        const float* kp = kT + (size_t)seq0 * 2048;
#pragma unroll
        for (int s = 0; s < 8; s++) zn[s] = make_float2(qp[t + 256 * s], kp[t + 256 * s]);
    }

    for (int j4 = 0; j4 < 4; j4++) {
        float2 z[8];
#pragma unroll
        for (int s = 0; s < 8; s++) z[s] = zn[s];
        if (j4 + 1 < 4) {            // issue next-seq loads; latency hides under rounds
            const int seq = bh * 64 + part * 4 + j4 + 1;
            const float* qp = qT + (size_t)seq * 2048;
            const float* kp = kT + (size_t)seq * 2048;
#pragma unroll
            for (int s = 0; s < 8; s++) zn[s] = make_float2(qp[t + 256 * s], kp[t + 256 * s]);
        }
        __syncthreads();   // Wt ready (iter 0); prev unpack reads done (iter >0)

        // ---- round 1 (bits 10,9,8), jb = t ----
#pragma unroll
        for (int sp = 0; sp < 4; sp++) {
            float2 u = z[sp], v = z[sp + 4];
            z[sp]     = cadd2(u, v);
            z[sp + 4] = cmul2(csub2(u, v), Wt[t + 256 * sp]);
        }
#pragma unroll
        for (int base = 0; base < 8; base += 4)
#pragma unroll
            for (int q2 = 0; q2 < 2; q2++) {
                float2 u = z[base + q2], v = z[base + q2 + 2];
                z[base + q2]     = cadd2(u, v);
                z[base + q2 + 2] = cmul2(csub2(u, v), Wt[2 * (t + 256 * q2)]);
            }
        {
            const float2 w = Wt[4 * t];
#pragma unroll
            for (int e = 0; e < 8; e += 2) {
                float2 u = z[e], v = z[e + 1];
                z[e]     = cadd2(u, v);
                z[e + 1] = cmul2(csub2(u, v), w);
            }
        }

        // exchange 1: (t+256s) -> (low5+32s+256hi3)
#pragma unroll
        for (int s = 0; s < 8; s++) Zs[PAD3(t + 256 * s)] = z[s];
        __syncthreads();
#pragma unroll
        for (int s = 0; s < 8; s++) z[s] = Zs[PAD3(low5 + 32 * s + 256 * hi3)];
        // no barrier: round-2 writes return to the same slots this thread read

        // ---- round 2 (bits 7,6,5), jb = low5 ----
#pragma unroll
        for (int sp = 0; sp < 4; sp++) {
            float2 u = z[sp], v = z[sp + 4];
            z[sp]     = cadd2(u, v);
            z[sp + 4] = cmul2(csub2(u, v), Wt[8 * (low5 + 32 * sp)]);
        }
#pragma unroll
        for (int base = 0; base < 8; base += 4)
#pragma unroll
            for (int q2 = 0; q2 < 2; q2++) {
                float2 u = z[base + q2], v = z[base + q2 + 2];
                z[base + q2]     = cadd2(u, v);
                z[base + q2 + 2] = cmul2(csub2(u, v), Wt[16 * (low5 + 32 * q2)]);
            }
        {
            const float2 w = Wt[32 * low5];
#pragma unroll
            for (int e = 0; e < 8; e += 2) {
                float2 u = z[e], v = z[e + 1];
                z[e]     = cadd2(u, v);
                z[e + 1] = cmul2(csub2(u, v), w);
            }
        }

        // exchange 2: (low5+32s+256hi3) -> (low2+4s+32hi6)
#pragma unroll
        for (int s = 0; s < 8; s++) Zs[PAD3(low5 + 32 * s + 256 * hi3)] = z[s];
        __syncthreads();
#pragma unroll
        for (int s = 0; s < 8; s++) z[s] = Zs[PAD3(low2 + 4 * s + 32 * hi6)];

        // ---- round 3 (bits 4,3,2), jb = low2 ----
#pragma unroll
        for (int sp = 0; sp < 4; sp++) {
            float2 u = z[sp], v = z[sp + 4];
            z[sp]     = cadd2(u, v);
            z[sp + 4] = cmul2(csub2(u, v), Wt[64 * (low2 + 4 * sp)]);
        }
#pragma unroll
        for (int base = 0; base < 8; base += 4)
#pragma unroll
            for (int q2 = 0; q2 < 2; q2++) {
                float2 u = z[base + q2], v = z[base + q2 + 2];
                z[base + q2]     = cadd2(u, v);
                z[base + q2 + 2] = cmul2(csub2(u, v), Wt[128 * (low2 + 4 * q2)]);
            }
        {
            const float2 w = Wt[256 * low2];
#pragma unroll
            for (int e = 0; e < 8; e += 2) {
                float2 u = z[e], v = z[e + 1];
                z[e]     = cadd2(u, v);
                z[e + 1] = cmul2(csub2(u, v), w);
            }
        }

        // exchange 3: (low2+4s+32hi6) -> (8t+s)
#pragma unroll
        for (int s = 0; s < 8; s++) Zs[PAD3(low2 + 4 * s + 32 * hi6)] = z[s];
        __syncthreads();
#pragma unroll
        for (int s = 0; s < 8; s++) z[s] = Zs[PAD3(8 * t + s)];

        // ---- round 4 (bits 1,0) ----
#pragma unroll
        for (int base = 0; base < 8; base += 4) {
            {
                float2 u = z[base], v = z[base + 2];
                z[base]     = cadd2(u, v);
                z[base + 2] = csub2(u, v);
            }
            {
                float2 u = z[base + 1], v = z[base + 3];
                float2 d = csub2(u, v);
                z[base + 1] = cadd2(u, v);
                z[base + 3] = make_float2(d.y, -d.x);
            }
        }
#pragma unroll
        for (int e = 0; e < 8; e += 2) {
            float2 u = z[e], v = z[e + 1];
            z[e]     = cadd2(u, v);
            z[e + 1] = csub2(u, v);
        }

        // write back completed FFT (same slots this thread read -> only one barrier)
#pragma unroll
        for (int s = 0; s < 8; s++) Zs[PAD3(8 * t + s)] = z[s];
        __syncthreads();

        // unpack q+ik; accumulate P at thread-fixed positions p = t+256s (registers)
#pragma unroll
        for (int s = 0; s < 8; s++) {
            const int p  = t + 256 * s;
            const int f  = (int)(__brev((unsigned)p) >> 21);
            const int fm = (2048 - f) & 2047;
            const int p2 = (int)(__brev((unsigned)fm) >> 21);
            const float2 zf = Zs[PAD3(p)];
            const float2 zm = Zs[PAD3(p2)];
            const float qr = 0.5f * (zf.x + zm.x);
            const float qi = 0.5f * (zf.y - zm.y);
            const float kr = 0.5f * (zf.y + zm.y);
            const float ki = 0.5f * (zm.x - zf.x);
            if (f != 0) {   // DC bin stays zero (mean subtraction)
                pacc[s].x += qr * kr + qi * ki;
                pacc[s].y += qi * kr - qr * ki;
            }
        }
    }

    // one coalesced partial-spectrum store (bit-rev position order)
    float2* outp = (float2*)specP + (size_t)blk * 2048;
#pragma unroll
    for (int s = 0; s < 8; s++) outp[t + 256 * s] = pacc[s];
}

// ---------------- inverse (DIT over bit-reversed input) helpers ----------------
__device__ inline void build_twiddle(float2* Wt, int tid, float sign) {
#pragma unroll
    for (int s = 0; s < 4; s++) {
        const int j = tid + s * 256;
        const float a = 2.0f * (float)M_PI * (float)j / 2048.0f;
        float sv, cv;
        __sincosf(a, &sv, &cv);
        Wt[j] = make_float2(cv, sign * sv);
    }
}

__device__ inline void fft2048_stages(float2* Z, const float2* Wt, int tid) {
    for (int st = 0; st < 11; st++) {
        const int half = 1 << st;
        const int shift = 10 - st;
#pragma unroll
        for (int r = 0; r < 4; r++) {
            const int m   = tid + r * 256;
            const int grp = m >> st;
            const int pos = m & (half - 1);
            const int i0  = (grp << (st + 1)) + pos;
            const int i1  = i0 + half;
            const float2 w = Wt[pos << shift];
            const float2 a = Z[i0];
            const float2 b = Z[i1];
            const float tr = b.x * w.x - b.y * w.y;
            const float ti = b.x * w.y + b.y * w.x;
            Z[i0] = make_float2(a.x + tr, a.y + ti);
            Z[i1] = make_float2(a.x - tr, a.y - ti);
        }
        __syncthreads();
    }
}

// ============ merged dispatch: blocks 0-63 = inverse FFT + top-8, 64-575 = V GEMM ============
// (data-independent halves; inv hides under the 512 v blocks)
__global__ __launch_bounds__(256, 3) void gemm_v_fftinv(const float* __restrict__ xkv,
                                                        const _Float16* __restrict__ Bh_g,
                                                        const float* __restrict__ bias,
                                                        _Float16* __restrict__ C,
                                                        const float* __restrict__ specP,
                                                        int* __restrict__ delays,
                                                        float* __restrict__ weights) {
    __shared__ __align__(16) char smem[24608];   // max(gemm 16384, inv 16384+8192+32)
    const int bid = blockIdx.x;
    const int tid = threadIdx.x;

    if (bid >= 64) {
        gemm_body<1, 2, 1, 32>(xkv, nullptr, nullptr, Bh_g, Bh_g, bias, C, (_Float16*)smem, bid - 64);
        return;
    }

    // ---------- inverse FFT + top-8 for bh = bid ----------
    const int bh = bid;
    float2* Z  = (float2*)smem;             // 2048 * 8B
    float2* Wt = (float2*)(smem + 16384);   // 1024 * 8B
    float*  wvs = (float*)(smem + 24576);   // 4 cross-wave candidates
    int*    wis = (int*)(smem + 24592);

    build_twiddle(Wt, tid, +1.0f);

    const float2* sp = (const float2*)specP + (size_t)bh * 16 * 2048;
#pragma unroll
    for (int s = 0; s < 8; s++) {
        const int p = tid + s * 256;
        float2 acc = make_float2(0.0f, 0.0f);
#pragma unroll
        for (int part = 0; part < 16; part++) {
            const float2 v = sp[part * 2048 + p];
            acc.x += v.x; acc.y += v.y;
        }
        Z[p] = acc;
    }
    __syncthreads();
    fft2048_stages(Z, Wt, tid);

    const float scale = 1.0f / (2048.0f * 64.0f);
    float cv[8];                    // this thread's corr values at p = tid + 256*s
#pragma unroll
    for (int s = 0; s < 8; s++) cv[s] = Z[tid + s * 256].x * scale;

    float bkv[KD];
    int   bki[KD];
#pragma unroll
    for (int k = 0; k < KD; k++) {
        float lv = -1e30f;
        int   li = 1 << 30;
#pragma unroll
        for (int s = 0; s < 8; s++) {
            const int idx = tid + s * 256;
            if (cv[s] > lv || (cv[s] == lv && idx < li)) { lv = cv[s]; li = idx; }
        }
#pragma unroll
        for (int off = 1; off < 64; off <<= 1) {
            const float v2 = __shfl_xor(lv, off);
            const int   i2 = __shfl_xor(li, off);
            if (v2 > lv || (v2 == lv && i2 < li)) { lv = v2; li = i2; }
        }
        if ((tid & 63) == 0) { wvs[tid >> 6] = lv; wis[tid >> 6] = li; }
        __syncthreads();
        float bv = wvs[0];
        int   bi = wis[0];
#pragma unroll
        for (int j = 1; j < 4; j++) {
            const float v2 = wvs[j];
            const int   i2 = wis[j];
            if (v2 > bv || (v2 == bv && i2 < bi)) { bv = v2; bi = i2; }
        }
        bkv[k] = bv;
        bki[k] = bi;
        if ((bi & 255) == tid) {            // owner retires its slot (regs: static index only)
            const int slot = bi >> 8;
#pragma unroll
            for (int s = 0; s < 8; s++)
                if (s == slot) cv[s] = -1e30f;
        }
        __syncthreads();                    // wvs/wis safe for reuse next iteration
    }

    if (tid == 0) {
        float sum = 0.0f;
#pragma unroll
        for (int k = 0; k < KD; k++) sum += bkv[k];
        const float inv = 1.0f / (sum + 1e-12f);
#pragma unroll
        for (int k = 0; k < KD; k++) {
            weights[bh * KD + k] = bkv[k] * inv;
            delays[bh * KD + k]  = bki[k];
        }
    }
}

extern "C" void kernel_launch(void* const* d_in, const int* in_sizes, int n_in,
                              void* d_out, int out_size, void* d_ws, size_t ws_size,
                              hipStream_t stream) {
    const float* x_q  = (const float*)d_in[0];
    const float* x_kv = (const float*)d_in[1];
    const float* Wq   = (const float*)d_in[2];
    const float* bq   = (const float*)d_in[3];
    const float* Wk   = (const float*)d_in[4];
    const float* bk   = (const float*)d_in[5];
    const float* Wv   = (const float*)d_in[6];
    const float* bv   = (const float*)d_in[7];
    const float* Wo   = (const float*)d_in[8];
    const float* bo   = (const float*)d_in[9];
    float* out = (float*)d_out;

    // ---- workspace layout: fully disjoint, no aliasing (peak 87.0 MB) ----
    // 0        .. 32 MiB : kf32 (k projection, fp32)
    // 32 MiB   .. 48 MiB : vh   (v projection, fp16)
    // 48 MiB   .. 64 MiB : specP (1024 FFT partials)
    // 64 MiB   .. 80 MiB : (free; was gbuf)
    // 80 MiB   ..        : weight hi/lo planes, dely, wgt
    // q lives in d_out (exactly 32 MiB) until fft_fwd consumes it; gemm_og rewrites d_out.
    char* ws = (char*)d_ws;
    float*    kf32  = (float*)   (ws + 0);
    _Float16* vh    = (_Float16*)(ws + 33554432);
    float*    specP = (float*)   (ws + 50331648);
    _Float16* Wq_h  = (_Float16*)(ws + 83886080);
    _Float16* Wq_l  = (_Float16*)(ws + 84410368);
    _Float16* Wk_h  = (_Float16*)(ws + 84934656);
    _Float16* Wk_l  = (_Float16*)(ws + 85458944);
    _Float16* Wv_h  = (_Float16*)(ws + 85983232);
    _Float16* Wo_h  = (_Float16*)(ws + 86507520);
    int*      dely  = (int*)     (ws + 87031808);
    float*    wgt   = (float*)   (ws + 87033856);
    float*    qf32  = (float*)d_out;

    dim3 blk(256);

    // weights-only prep (x tensors consumed as fp32 directly by the GEMMs)
    prep_w<<<dim3(512), blk, 0, stream>>>(Wq, Wk, Wv, Wo,
                                          Wq_h, Wq_l, Wk_h, Wk_l, Wv_h, Wo_h);

    // merged q+k projections (hi/lo, A pipelined from fp32, BK=64)
    gemm_qk<<<dim3(1024), blk, 0, stream>>>(x_q,  Wq_h, Wq_l, bq, qf32,
                                            x_kv, Wk_h, Wk_l, bk, kf32);

    // forward FFTs: 1024 blocks × 4 sequences -> 16 partials/bh (no atomics)
    fft_fwd<<<dim3(1024), blk, 0, stream>>>(qf32, kf32, specP);

    // merged: inverse FFT + top-8 (blocks 0-63) hidden under v projection (blocks 64-575)
    gemm_v_fftinv<<<dim3(576), blk, 0, stream>>>(x_kv, Wv_h, bv, vh, specP, dely, wgt);

    // fused gather + output projection -> fp32 output (d_out; qf32 dead)
    gemm_og<<<dim3(512), blk, 0, stream>>>(vh, dely, wgt, Wo_h, bo, out);
}

// Round 11
// 251.995 us; speedup vs baseline: 1.0671x; 1.0671x over previous
//
#include <hip/hip_runtime.h>
#include <math.h>

#define BB 8
#define LL 2048
#define DD 512
#define HH 8
#define DHH 64
#define KD 8
#define MM (BB*LL)   // 16384

typedef _Float16 f16x2 __attribute__((ext_vector_type(2)));
typedef _Float16 f16x4 __attribute__((ext_vector_type(4)));
typedef _Float16 f16x8 __attribute__((ext_vector_type(8)));
typedef float    f32x4 __attribute__((ext_vector_type(4)));

// ---------------- prep: weights only, fp32 -> fp16 hi/lo ----------------
__device__ inline void cvt8(const float* __restrict__ s, _Float16* hp, _Float16* lp) {
    const float4 a = *(const float4*)s;
    const float4 b = *(const float4*)(s + 4);
    const float v[8] = {a.x, a.y, a.z, a.w, b.x, b.y, b.z, b.w};
    f16x8 hi, lo;
#pragma unroll
    for (int j = 0; j < 8; j++) {
        const _Float16 h = (_Float16)v[j];
        hi[j] = h;
        lo[j] = (_Float16)((v[j] - (float)h) * 512.0f);
    }
    *(f16x8*)hp = hi;
    if (lp) *(f16x8*)lp = lo;
}

__global__ __launch_bounds__(256) void prep_w(const float* __restrict__ Wq, const float* __restrict__ Wk,
                                              const float* __restrict__ Wv, const float* __restrict__ Wo,
                                              _Float16* __restrict__ Wq_h, _Float16* __restrict__ Wq_l,
                                              _Float16* __restrict__ Wk_h, _Float16* __restrict__ Wk_l,
                                              _Float16* __restrict__ Wv_h, _Float16* __restrict__ Wo_h) {
    const int g = blockIdx.x * 256 + threadIdx.x;   // 131072 threads × 8 elems
    const int which = g >> 15;
    const size_t idx = (size_t)(g & 32767) * 8;
    if (which == 0)      cvt8(Wq + idx, Wq_h + idx, Wq_l + idx);
    else if (which == 1) cvt8(Wk + idx, Wk_h + idx, Wk_l + idx);
    else if (which == 2) cvt8(Wv + idx, Wv_h + idx, nullptr);
    else                 cvt8(Wo + idx, Wo_h + idx, nullptr);
}

// ---------------- async global->LDS staging (DMA, no VGPR round-trip) ----------------
__device__ __forceinline__ void stage16(const _Float16* g, const _Float16* l) {
    __builtin_amdgcn_global_load_lds(
        (const __attribute__((address_space(1))) void*)g,
        (__attribute__((address_space(3))) void*)l,
        16, 0, 0);
}

// ---------------- MFMA GEMM body (device fn): C = A @ B^T + bias ----------------
// Templated K-step BK (32 or 64). BK=64 halves barrier count; chunk-XOR swizzle
// (2-way bank alias = free). B staged via global_load_lds width=16; A (AF32=1)
// software-pipelined from fp32 (next-step loads issued at start of MFMA phase).
template<int NPROD, int MODE, int AF32, int BK>
__device__ __forceinline__ void gemm_body(const float* __restrict__ A32,
                                          const _Float16* __restrict__ Ag,
                                          const _Float16* __restrict__ Al_g,
                                          const _Float16* __restrict__ Bg,
                                          const _Float16* __restrict__ Bl_g,
                                          const float* __restrict__ bias,
                                          void* __restrict__ Cv,
                                          _Float16* lds, int l0) {
    constexpr int CPR  = BK / 8;        // chunks (16B) per row
    constexpr int NST  = BK / 16;       // staging iterations per plane
    constexpr int SH   = (BK == 32) ? 2 : 3;
    constexpr int PLN  = 128 * BK;      // plane size in halves

#define SWZR(R) ((BK == 32) ? (((R) >> 1) & 3) : ((R) & 7))
#define ASWZ(R, g) ((size_t)(R) * BK + (size_t)((((g) ^ SWZR(R))) * 8))

    _Float16* Ah = lds;
    _Float16* Bh = lds + PLN;
    _Float16* Al = (NPROD == 3) ? lds + 2 * PLN : lds;
    _Float16* Bl = (NPROD == 3) ? lds + 3 * PLN : lds;

    const int t  = threadIdx.x;
    const int m0 = (((l0 >> 5) << 3) | (l0 & 7)) * 128;   // XCD-aware swizzle
    const int n0 = ((l0 >> 3) & 3) * 128;

    const int wv   = t >> 6;
    const int lane = t & 63;
    const int wm   = (wv >> 1) * 64;
    const int wn   = (wv & 1) * 64;
    const int lm   = lane & 15;
    const int quad = lane >> 4;

    // staging geometry: wave wv, iter i covers LDS slots s = (i*4+wv)*64 + lane
    int srow[NST], schk[NST], sgrp[NST];
#pragma unroll
    for (int i = 0; i < NST; i++) {
        const int s = (i * 4 + wv) * 64 + lane;
        srow[i] = s >> SH;
        schk[i] = (s & (CPR - 1)) ^ SWZR(srow[i]);
        sgrp[i] = (i * 4 + wv) * 512;    // wave-uniform LDS base (halves)
    }

    f32x4 acc0[4][4] = {};
    f32x4 acc1[4][4] = {};

    // A fp32 pipeline registers (loaded one K-step ahead)
    float4 vaA[NST], vaB[NST];
    if (AF32) {
#pragma unroll
        for (int i = 0; i < NST; i++) {
            const float* src = A32 + (size_t)(m0 + srow[i]) * 512 + schk[i] * 8;
            vaA[i] = *(const float4*)src;
            vaB[i] = *(const float4*)(src + 4);
        }
    }

    for (int k0 = 0; k0 < 512; k0 += BK) {
        __syncthreads();   // previous iteration's fragment reads complete
#pragma unroll
        for (int i = 0; i < NST; i++) {
            const size_t offB = (size_t)(n0 + srow[i]) * 512 + k0 + schk[i] * 8;
            stage16(Bg + offB, Bh + sgrp[i]);
            if (NPROD == 3) stage16(Bl_g + offB, Bl + sgrp[i]);
            if (AF32) {
                const float va[8] = {vaA[i].x, vaA[i].y, vaA[i].z, vaA[i].w,
                                     vaB[i].x, vaB[i].y, vaB[i].z, vaB[i].w};
                f16x8 hi, lo;
#pragma unroll
                for (int j = 0; j < 8; j++) {
                    const _Float16 h = (_Float16)va[j];
                    hi[j] = h;
                    if (NPROD == 3) lo[j] = (_Float16)((va[j] - (float)h) * 512.0f);
                }
                *(f16x8*)&Ah[sgrp[i] + lane * 8] = hi;
                if (NPROD == 3) *(f16x8*)&Al[sgrp[i] + lane * 8] = lo;
            } else {
                const size_t offA = (size_t)(m0 + srow[i]) * 512 + k0 + schk[i] * 8;
                stage16(Ag + offA, Ah + sgrp[i]);
                if (NPROD == 3) stage16(Al_g + offA, Al + sgrp[i]);
            }
        }
        __syncthreads();   // vmcnt+lgkmcnt drain before barrier (compiler)

        if (AF32 && k0 + BK < 512) {   // issue next-step A loads; hide under MFMA phase
#pragma unroll
            for (int i = 0; i < NST; i++) {
                const float* src = A32 + (size_t)(m0 + srow[i]) * 512 + (k0 + BK) + schk[i] * 8;
                vaA[i] = *(const float4*)src;
                vaB[i] = *(const float4*)(src + 4);
            }
        }

#pragma unroll
        for (int ks = 0; ks < BK / 32; ks++) {
            const int gq = ks * 4 + quad;     // k-chunk for this 32-k slice
            f16x8 afh[4], bf[4];
#pragma unroll
            for (int mt = 0; mt < 4; mt++)
                afh[mt] = *(f16x8*)&Ah[ASWZ(wm + mt * 16 + lm, gq)];
#pragma unroll
            for (int nt = 0; nt < 4; nt++)
                bf[nt] = *(f16x8*)&Bh[ASWZ(wn + nt * 16 + lm, gq)];

#pragma unroll
            for (int mt = 0; mt < 4; mt++)
#pragma unroll
                for (int nt = 0; nt < 4; nt++)
                    acc0[mt][nt] = __builtin_amdgcn_mfma_f32_16x16x32_f16(afh[mt], bf[nt], acc0[mt][nt], 0, 0, 0);

            if (NPROD == 3) {
                f16x8 afl[4];
#pragma unroll
                for (int mt = 0; mt < 4; mt++)
                    afl[mt] = *(f16x8*)&Al[ASWZ(wm + mt * 16 + lm, gq)];
#pragma unroll
                for (int mt = 0; mt < 4; mt++)
#pragma unroll
                    for (int nt = 0; nt < 4; nt++)
                        acc1[mt][nt] = __builtin_amdgcn_mfma_f32_16x16x32_f16(afl[mt], bf[nt], acc1[mt][nt], 0, 0, 0);
#pragma unroll
                for (int nt = 0; nt < 4; nt++)
                    bf[nt] = *(f16x8*)&Bl[ASWZ(wn + nt * 16 + lm, gq)];
#pragma unroll
                for (int mt = 0; mt < 4; mt++)
#pragma unroll
                    for (int nt = 0; nt < 4; nt++)
                        acc1[mt][nt] = __builtin_amdgcn_mfma_f32_16x16x32_f16(afh[mt], bf[nt], acc1[mt][nt], 0, 0, 0);
            }
        }
    }
#undef ASWZ
#undef SWZR

    // epilogue: C/D layout col=lane&15, row=quad*4+reg
#pragma unroll
    for (int mt = 0; mt < 4; mt++) {
#pragma unroll
        for (int nt = 0; nt < 4; nt++) {
            const int n = n0 + wn + nt * 16 + lm;
            const float bv = bias[n];
            float val[4];
#pragma unroll
            for (int r = 0; r < 4; r++) {
                val[r] = acc0[mt][nt][r] + bv;
                if (NPROD == 3) val[r] += acc1[mt][nt][r] * (1.0f / 512.0f);
            }
            const int mbase = m0 + wm + mt * 16 + quad * 4;   // multiple of 4
            const int b_idx = mbase >> 11;
            const int lbase = mbase & 2047;
            if (MODE == 0) {
                float* C = (float*)Cv;
#pragma unroll
                for (int r = 0; r < 4; r++) C[(size_t)(mbase + r) * 512 + n] = val[r];
            } else if (MODE == 1) {
                float* C = (float*)Cv;
                float4 pv = make_float4(val[0], val[1], val[2], val[3]);
                *(float4*)&C[((size_t)(b_idx * 512 + n)) * 2048 + lbase] = pv;
            } else {
                _Float16* C = (_Float16*)Cv;
#pragma unroll
                for (int r = 0; r < 4; r++)
                    C[(size_t)b_idx * 1048576 + (size_t)(n >> 6) * 131072
                      + (size_t)(lbase + r) * 64 + (n & 63)] = (_Float16)val[r];
            }
        }
    }
}

// merged q+k projection: 1024 blocks; 0-511 = q (A=x_q fp32), 512-1023 = k (A=x_kv fp32)
__global__ __launch_bounds__(256, 2) void gemm_qk(const float* __restrict__ A0f,
                                                  const _Float16* __restrict__ B0h, const _Float16* __restrict__ B0l,
                                                  const float* __restrict__ bias0, float* __restrict__ C0,
                                                  const float* __restrict__ A1f,
                                                  const _Float16* __restrict__ B1h, const _Float16* __restrict__ B1l,
                                                  const float* __restrict__ bias1, float* __restrict__ C1) {
    __shared__ __align__(16) _Float16 lds[32768];   // 4 planes x 16KB = 64KB
    const int prob = blockIdx.x >> 9;
    const int l0   = blockIdx.x & 511;
    if (prob == 0)
        gemm_body<3, 1, 1, 64>(A0f, nullptr, nullptr, B0h, B0l, bias0, C0, lds, l0);
    else
        gemm_body<3, 1, 1, 64>(A1f, nullptr, nullptr, B1h, B1l, bias1, C1, lds, l0);
}

// output projection from prepped f16 gather buffer; BK=64 halves barrier count.
__global__ __launch_bounds__(256, 3) void gemm_o(const _Float16* __restrict__ Ah_g,
                                                 const _Float16* __restrict__ Bh_g,
                                                 const float* __restrict__ bias,
                                                 float* __restrict__ C) {
    __shared__ __align__(16) _Float16 lds[16384];   // 2 planes x 16KB = 32KB
    gemm_body<1, 0, 0, 64>(nullptr, Ah_g, Ah_g, Bh_g, Bh_g, bias, C, lds, blockIdx.x);
}

// ============== register-resident radix-8 DIF forward FFT (N=2048), fp32 in ==============
// 1024 blocks × 4 sequences. Next-seq loads prefetched across the butterfly rounds.
#define PAD3(i) ((i) + ((i) >> 3))

__device__ inline float2 cmul2(float2 a, float2 w) {
    return make_float2(a.x * w.x - a.y * w.y, a.x * w.y + a.y * w.x);
}
__device__ inline float2 cadd2(float2 a, float2 b) { return make_float2(a.x + b.x, a.y + b.y); }
__device__ inline float2 csub2(float2 a, float2 b) { return make_float2(a.x - b.x, a.y - b.y); }

__global__ __launch_bounds__(256) void fft_fwd(const float* __restrict__ qT,
                                               const float* __restrict__ kT,
                                               float* __restrict__ specP) {
    const int blk  = blockIdx.x;     // bh*16 + part
    const int bh   = blk >> 4;
    const int part = blk & 15;
    const int t    = threadIdx.x;
    __shared__ float2 Zs[2304];      // PAD3(2047) = 2302
    __shared__ float2 Wt[1024];      // Wt[j] = exp(-2*pi*i*j/2048)

#pragma unroll
    for (int s = 0; s < 4; s++) {
        const int j = t + s * 256;
        float sv, cv;
        __sincosf(2.0f * (float)M_PI * (float)j / 2048.0f, &sv, &cv);
        Wt[j] = make_float2(cv, -sv);
    }

    float2 pacc[8];
#pragma unroll
    for (int s = 0; s < 8; s++) pacc[s] = make_float2(0.0f, 0.0f);

    const int low5 = t & 31, hi3 = t >> 5;
    const int low2 = t & 3,  hi6 = t >> 2;

    // prefetch first sequence
    float2 zn[8];
    {
        const int seq0 = bh * 64 + part * 4;
        const float* qp = qT + (size_t)seq0 * 2048;
        const float* kp = kT + (size_t)seq0 * 2048;
#pragma unroll
        for (int s = 0; s < 8; s++) zn[s] = make_float2(qp[t + 256 * s], kp[t + 256 * s]);
    }

    for (int j4 = 0; j4 < 4; j4++) {
        float2 z[8];
#pragma unroll
        for (int s = 0; s < 8; s++) z[s] = zn[s];
        if (j4 + 1 < 4) {            // issue next-seq loads; latency hides under rounds
            const int seq = bh * 64 + part * 4 + j4 + 1;
            const float* qp = qT + (size_t)seq * 2048;
            const float* kp = kT + (size_t)seq * 2048;
#pragma unroll
            for (int s = 0; s < 8; s++) zn[s] = make_float2(qp[t + 256 * s], kp[t + 256 * s]);
        }
        __syncthreads();   // Wt ready (iter 0); prev unpack reads done (iter >0)

        // ---- round 1 (bits 10,9,8), jb = t ----
#pragma unroll
        for (int sp = 0; sp < 4; sp++) {
            float2 u = z[sp], v = z[sp + 4];
            z[sp]     = cadd2(u, v);
            z[sp + 4] = cmul2(csub2(u, v), Wt[t + 256 * sp]);
        }
#pragma unroll
        for (int base = 0; base < 8; base += 4)
#pragma unroll
            for (int q2 = 0; q2 < 2; q2++) {
                float2 u = z[base + q2], v = z[base + q2 + 2];
                z[base + q2]     = cadd2(u, v);
                z[base + q2 + 2] = cmul2(csub2(u, v), Wt[2 * (t + 256 * q2)]);
            }
        {
            const float2 w = Wt[4 * t];
#pragma unroll
            for (int e = 0; e < 8; e += 2) {
                float2 u = z[e], v = z[e + 1];
                z[e]     = cadd2(u, v);
                z[e + 1] = cmul2(csub2(u, v), w);
            }
        }

        // exchange 1: (t+256s) -> (low5+32s+256hi3)
#pragma unroll
        for (int s = 0; s < 8; s++) Zs[PAD3(t + 256 * s)] = z[s];
        __syncthreads();
#pragma unroll
        for (int s = 0; s < 8; s++) z[s] = Zs[PAD3(low5 + 32 * s + 256 * hi3)];
        // no barrier: round-2 writes return to the same slots this thread read

        // ---- round 2 (bits 7,6,5), jb = low5 ----
#pragma unroll
        for (int sp = 0; sp < 4; sp++) {
            float2 u = z[sp], v = z[sp + 4];
            z[sp]     = cadd2(u, v);
            z[sp + 4] = cmul2(csub2(u, v), Wt[8 * (low5 + 32 * sp)]);
        }
#pragma unroll
        for (int base = 0; base < 8; base += 4)
#pragma unroll
            for (int q2 = 0; q2 < 2; q2++) {
                float2 u = z[base + q2], v = z[base + q2 + 2];
                z[base + q2]     = cadd2(u, v);
                z[base + q2 + 2] = cmul2(csub2(u, v), Wt[16 * (low5 + 32 * q2)]);
            }
        {
            const float2 w = Wt[32 * low5];
#pragma unroll
            for (int e = 0; e < 8; e += 2) {
                float2 u = z[e], v = z[e + 1];
                z[e]     = cadd2(u, v);
                z[e + 1] = cmul2(csub2(u, v), w);
            }
        }

        // exchange 2: (low5+32s+256hi3) -> (low2+4s+32hi6)
#pragma unroll
        for (int s = 0; s < 8; s++) Zs[PAD3(low5 + 32 * s + 256 * hi3)] = z[s];
        __syncthreads();
#pragma unroll
        for (int s = 0; s < 8; s++) z[s] = Zs[PAD3(low2 + 4 * s + 32 * hi6)];

        // ---- round 3 (bits 4,3,2), jb = low2 ----
#pragma unroll
        for (int sp = 0; sp < 4; sp++) {
            float2 u = z[sp], v = z[sp + 4];
            z[sp]     = cadd2(u, v);
            z[sp + 4] = cmul2(csub2(u, v), Wt[64 * (low2 + 4 * sp)]);
        }
#pragma unroll
        for (int base = 0; base < 8; base += 4)
#pragma unroll
            for (int q2 = 0; q2 < 2; q2++) {
                float2 u = z[base + q2], v = z[base + q2 + 2];
                z[base + q2]     = cadd2(u, v);
                z[base + q2 + 2] = cmul2(csub2(u, v), Wt[128 * (low2 + 4 * q2)]);
            }
        {
            const float2 w = Wt[256 * low2];
#pragma unroll
            for (int e = 0; e < 8; e += 2) {
                float2 u = z[e], v = z[e + 1];
                z[e]     = cadd2(u, v);
                z[e + 1] = cmul2(csub2(u, v), w);
            }
        }

        // exchange 3: (low2+4s+32hi6) -> (8t+s)
#pragma unroll
        for (int s = 0; s < 8; s++) Zs[PAD3(low2 + 4 * s + 32 * hi6)] = z[s];
        __syncthreads();
#pragma unroll
        for (int s = 0; s < 8; s++) z[s] = Zs[PAD3(8 * t + s)];

        // ---- round 4 (bits 1,0) ----
#pragma unroll
        for (int base = 0; base < 8; base += 4) {
            {
                float2 u = z[base], v = z[base + 2];
                z[base]     = cadd2(u, v);
                z[base + 2] = csub2(u, v);
            }
            {
                float2 u = z[base + 1], v = z[base + 3];
                float2 d = csub2(u, v);
                z[base + 1] = cadd2(u, v);
                z[base + 3] = make_float2(d.y, -d.x);
            }
        }
#pragma unroll
        for (int e = 0; e < 8; e += 2) {
            float2 u = z[e], v = z[e + 1];
            z[e]     = cadd2(u, v);
            z[e + 1] = csub2(u, v);
        }

        // write back completed FFT (same slots this thread read -> only one barrier)
#pragma unroll
        for (int s = 0; s < 8; s++) Zs[PAD3(8 * t + s)] = z[s];
        __syncthreads();

        // unpack q+ik; accumulate P at thread-fixed positions p = t+256s (registers)
#pragma unroll
        for (int s = 0; s < 8; s++) {
            const int p  = t + 256 * s;
            const int f  = (int)(__brev((unsigned)p) >> 21);
            const int fm = (2048 - f) & 2047;
            const int p2 = (int)(__brev((unsigned)fm) >> 21);
            const float2 zf = Zs[PAD3(p)];
            const float2 zm = Zs[PAD3(p2)];
            const float qr = 0.5f * (zf.x + zm.x);
            const float qi = 0.5f * (zf.y - zm.y);
            const float kr = 0.5f * (zf.y + zm.y);
            const float ki = 0.5f * (zm.x - zf.x);
            if (f != 0) {   // DC bin stays zero (mean subtraction)
                pacc[s].x += qr * kr + qi * ki;
                pacc[s].y += qi * kr - qr * ki;
            }
        }
    }

    // one coalesced partial-spectrum store (bit-rev position order)
    float2* outp = (float2*)specP + (size_t)blk * 2048;
#pragma unroll
    for (int s = 0; s < 8; s++) outp[t + 256 * s] = pacc[s];
}

// ---------------- inverse (DIT over bit-reversed input) helpers ----------------
__device__ inline void build_twiddle(float2* Wt, int tid, float sign) {
#pragma unroll
    for (int s = 0; s < 4; s++) {
        const int j = tid + s * 256;
        const float a = 2.0f * (float)M_PI * (float)j / 2048.0f;
        float sv, cv;
        __sincosf(a, &sv, &cv);
        Wt[j] = make_float2(cv, sign * sv);
    }
}

__device__ inline void fft2048_stages(float2* Z, const float2* Wt, int tid) {
    for (int st = 0; st < 11; st++) {
        const int half = 1 << st;
        const int shift = 10 - st;
#pragma unroll
        for (int r = 0; r < 4; r++) {
            const int m   = tid + r * 256;
            const int grp = m >> st;
            const int pos = m & (half - 1);
            const int i0  = (grp << (st + 1)) + pos;
            const int i1  = i0 + half;
            const float2 w = Wt[pos << shift];
            const float2 a = Z[i0];
            const float2 b = Z[i1];
            const float tr = b.x * w.x - b.y * w.y;
            const float ti = b.x * w.y + b.y * w.x;
            Z[i0] = make_float2(a.x + tr, a.y + ti);
            Z[i1] = make_float2(a.x - tr, a.y - ti);
        }
        __syncthreads();
    }
}

// ============ merged dispatch: blocks 0-63 = inverse FFT + top-8, 64-575 = V GEMM ============
// (data-independent halves; inv hides under the 512 v blocks)
__global__ __launch_bounds__(256, 3) void gemm_v_fftinv(const float* __restrict__ xkv,
                                                        const _Float16* __restrict__ Bh_g,
                                                        const float* __restrict__ bias,
                                                        _Float16* __restrict__ C,
                                                        const float* __restrict__ specP,
                                                        int* __restrict__ delays,
                                                        float* __restrict__ weights) {
    __shared__ __align__(16) char smem[24608];   // max(gemm 16384, inv 16384+8192+32)
    const int bid = blockIdx.x;
    const int tid = threadIdx.x;

    if (bid >= 64) {
        gemm_body<1, 2, 1, 32>(xkv, nullptr, nullptr, Bh_g, Bh_g, bias, C, (_Float16*)smem, bid - 64);
        return;
    }

    // ---------- inverse FFT + top-8 for bh = bid ----------
    const int bh = bid;
    float2* Z  = (float2*)smem;             // 2048 * 8B
    float2* Wt = (float2*)(smem + 16384);   // 1024 * 8B
    float*  wvs = (float*)(smem + 24576);   // 4 cross-wave candidates
    int*    wis = (int*)(smem + 24592);

    build_twiddle(Wt, tid, +1.0f);

    const float2* sp = (const float2*)specP + (size_t)bh * 16 * 2048;
#pragma unroll
    for (int s = 0; s < 8; s++) {
        const int p = tid + s * 256;
        float2 acc = make_float2(0.0f, 0.0f);
#pragma unroll
        for (int part = 0; part < 16; part++) {
            const float2 v = sp[part * 2048 + p];
            acc.x += v.x; acc.y += v.y;
        }
        Z[p] = acc;
    }
    __syncthreads();
    fft2048_stages(Z, Wt, tid);

    const float scale = 1.0f / (2048.0f * 64.0f);
    float cv[8];                    // this thread's corr values at p = tid + 256*s
#pragma unroll
    for (int s = 0; s < 8; s++) cv[s] = Z[tid + s * 256].x * scale;

    float bkv[KD];
    int   bki[KD];
#pragma unroll
    for (int k = 0; k < KD; k++) {
        float lv = -1e30f;
        int   li = 1 << 30;
#pragma unroll
        for (int s = 0; s < 8; s++) {
            const int idx = tid + s * 256;
            if (cv[s] > lv || (cv[s] == lv && idx < li)) { lv = cv[s]; li = idx; }
        }
#pragma unroll
        for (int off = 1; off < 64; off <<= 1) {
            const float v2 = __shfl_xor(lv, off);
            const int   i2 = __shfl_xor(li, off);
            if (v2 > lv || (v2 == lv && i2 < li)) { lv = v2; li = i2; }
        }
        if ((tid & 63) == 0) { wvs[tid >> 6] = lv; wis[tid >> 6] = li; }
        __syncthreads();
        float bv = wvs[0];
        int   bi = wis[0];
#pragma unroll
        for (int j = 1; j < 4; j++) {
            const float v2 = wvs[j];
            const int   i2 = wis[j];
            if (v2 > bv || (v2 == bv && i2 < bi)) { bv = v2; bi = i2; }
        }
        bkv[k] = bv;
        bki[k] = bi;
        if ((bi & 255) == tid) {            // owner retires its slot (regs: static index only)
            const int slot = bi >> 8;
#pragma unroll
            for (int s = 0; s < 8; s++)
                if (s == slot) cv[s] = -1e30f;
        }
        __syncthreads();                    // wvs/wis safe for reuse next iteration
    }

    if (tid == 0) {
        float sum = 0.0f;
#pragma unroll
        for (int k = 0; k < KD; k++) sum += bkv[k];
        const float inv = 1.0f / (sum + 1e-12f);
#pragma unroll
        for (int k = 0; k < KD; k++) {
            weights[bh * KD + k] = bkv[k] * inv;
            delays[bh * KD + k]  = bki[k];
        }
    }
}

// weighted circular-shift gather, fp16 in/out, 8 dh per thread (16B loads/stores)
__global__ __launch_bounds__(256) void gather_ws(const _Float16* __restrict__ v,
                                                 const int* __restrict__ delays,
                                                 const float* __restrict__ weights,
                                                 _Float16* __restrict__ outb) {
    const int gp = blockIdx.x * 256 + threadIdx.x;   // over M*64 = 1048576
    const int c8 = gp & 63;
    const int m  = gp >> 6;
    const int l  = m & 2047;
    const int b  = m >> 11;
    const int ch = c8 * 8;
    const int h  = ch >> 6;
    const int dh = ch & 63;
    const int bh = b * 8 + h;

    const _Float16* vb = v + (size_t)bh * 131072;
    float a[8] = {};
#pragma unroll
    for (int k = 0; k < KD; k++) {
        const int   d = delays[bh * KD + k];
        const float w = weights[bh * KD + k];
        const int   p = (l + d) & 2047;
        const f16x8 pv = *(const f16x8*)&vb[p * 64 + dh];
#pragma unroll
        for (int j = 0; j < 8; j++) a[j] = fmaf(w, (float)pv[j], a[j]);
    }
    f16x8 ov;
#pragma unroll
    for (int j = 0; j < 8; j++) ov[j] = (_Float16)a[j];
    *(f16x8*)&outb[(size_t)m * 512 + ch] = ov;
}

extern "C" void kernel_launch(void* const* d_in, const int* in_sizes, int n_in,
                              void* d_out, int out_size, void* d_ws, size_t ws_size,
                              hipStream_t stream) {
    const float* x_q  = (const float*)d_in[0];
    const float* x_kv = (const float*)d_in[1];
    const float* Wq   = (const float*)d_in[2];
    const float* bq   = (const float*)d_in[3];
    const float* Wk   = (const float*)d_in[4];
    const float* bk   = (const float*)d_in[5];
    const float* Wv   = (const float*)d_in[6];
    const float* bv   = (const float*)d_in[7];
    const float* Wo   = (const float*)d_in[8];
    const float* bo   = (const float*)d_in[9];
    float* out = (float*)d_out;

    // ---- workspace layout: fully disjoint, no aliasing (peak 87.0 MB) ----
    // 0        .. 32 MiB : kf32 (k projection, fp32)
    // 32 MiB   .. 48 MiB : vh   (v projection, fp16)
    // 48 MiB   .. 64 MiB : specP (1024 FFT partials)
    // 64 MiB   .. 80 MiB : gbuf (gathered A for output GEMM)
    // 80 MiB   ..        : weight hi/lo planes, dely, wgt
    // q lives in d_out (exactly 32 MiB) until fft_fwd consumes it; gemm_o rewrites d_out.
    char* ws = (char*)d_ws;
    float*    kf32  = (float*)   (ws + 0);
    _Float16* vh    = (_Float16*)(ws + 33554432);
    float*    specP = (float*)   (ws + 50331648);
    _Float16* gbuf  = (_Float16*)(ws + 67108864);
    _Float16* Wq_h  = (_Float16*)(ws + 83886080);
    _Float16* Wq_l  = (_Float16*)(ws + 84410368);
    _Float16* Wk_h  = (_Float16*)(ws + 84934656);
    _Float16* Wk_l  = (_Float16*)(ws + 85458944);
    _Float16* Wv_h  = (_Float16*)(ws + 85983232);
    _Float16* Wo_h  = (_Float16*)(ws + 86507520);
    int*      dely  = (int*)     (ws + 87031808);
    float*    wgt   = (float*)   (ws + 87033856);
    float*    qf32  = (float*)d_out;

    dim3 blk(256);

    // weights-only prep (x tensors consumed as fp32 directly by the GEMMs)
    prep_w<<<dim3(512), blk, 0, stream>>>(Wq, Wk, Wv, Wo,
                                          Wq_h, Wq_l, Wk_h, Wk_l, Wv_h, Wo_h);

    // merged q+k projections (hi/lo, A pipelined from fp32, BK=64)
    gemm_qk<<<dim3(1024), blk, 0, stream>>>(x_q,  Wq_h, Wq_l, bq, qf32,
                                            x_kv, Wk_h, Wk_l, bk, kf32);

    // forward FFTs: 1024 blocks × 4 sequences -> 16 partials/bh (no atomics)
    fft_fwd<<<dim3(1024), blk, 0, stream>>>(qf32, kf32, specP);

    // merged: inverse FFT + top-8 (blocks 0-63) hidden under v projection (blocks 64-575)
    gemm_v_fftinv<<<dim3(576), blk, 0, stream>>>(x_kv, Wv_h, bv, vh, specP, dely, wgt);

    // weighted circular gather -> fp16 [B,L,D]
    gather_ws<<<dim3(4096), blk, 0, stream>>>(vh, dely, wgt, gbuf);

    // final projection -> fp32 output (d_out; qf32 dead), BK=64
    gemm_o<<<dim3(512), blk, 0, stream>>>(gbuf, Wo_h, bo, out);
}